// Round 4
// baseline (410.255 us; speedup 1.0000x reference)
//
#include <hip/hip_runtime.h>
#include <hip/hip_bf16.h>

// USMSharp R4: separable Gaussian pipeline, bf16 intermediates, LDS-tiled vblur.
// K1 hblur(img f32)->A bf16 ; K2 vblur_tile(A) -> r = img - blur (bf16 only)
// K3 hblur(mask(|r|*255>10)) -> Bh bf16 (aliases A) ; K4 vblur_tile(Bh)+blend.
// ws: A/Bh u16[TOT] | r u16[TOT] | k1 f32[64]  = 49.8 MB.

#define W 1920
#define H 1080
#define NP 6
#define PLANE (H * W)
#define TOT (NP * PLANE)
#define R 25
#define KS 51
#define HCOLS 1024
#define CT 128            // vertical tile cols (1920 = 15*128)
#define RT 72             // vertical tile rows (1080 = 15*72)
#define SR (RT + 2 * R)   // 122 staged rows

__device__ __forceinline__ int reflect_idx(int i, int n) {
    if (i < 0) i = -i;
    if (i >= n) i = 2 * n - 2 - i;
    return i;
}
__device__ __forceinline__ float bf2f(unsigned short u) {
    return __uint_as_float(((unsigned int)u) << 16);
}
__device__ __forceinline__ unsigned short f2bf(float f) {  // RNE
    unsigned int x = __float_as_uint(f);
    return (unsigned short)((x + 0x7FFFu + ((x >> 16) & 1u)) >> 16);
}

__global__ void compute_k1(const float* __restrict__ k2d, float* __restrict__ k1) {
    int t = threadIdx.x;
    if (t < KS) {
        float s = 0.f;
        for (int j = 0; j < KS; ++j) s += k2d[t * KS + j];
        k1[t] = s;
    }
}

// ---- horizontal blur core: row[] staged, 4 outputs/thread -------------------
__device__ __forceinline__ void hconv_store(const float* __restrict__ row, int tid,
                                            const float* __restrict__ k1g,
                                            unsigned short* __restrict__ out,
                                            size_t obase, int x0) {
    const int x4 = x0 + 4 * tid;
    if (x4 >= W) return;
    float a0 = 0.f, a1 = 0.f, a2 = 0.f, a3 = 0.f;
#pragma unroll
    for (int i = 0; i < 14; ++i) {
        float4 v = *(const float4*)&row[4 * tid + 4 * i];
#pragma unroll
        for (int j = 0; j < 4; ++j) {
            const int p = 4 * i + j;
            const float vv = (j == 0) ? v.x : (j == 1) ? v.y : (j == 2) ? v.z : v.w;
            if (p <= 50) a0 += k1g[p] * vv;
            if (p - 1 >= 0 && p - 1 <= 50) a1 += k1g[p - 1] * vv;
            if (p - 2 >= 0 && p - 2 <= 50) a2 += k1g[p - 2] * vv;
            if (p - 3 >= 0 && p - 3 <= 50) a3 += k1g[p - 3] * vv;
        }
    }
    ushort4 o;
    o.x = f2bf(a0); o.y = f2bf(a1); o.z = f2bf(a2); o.w = f2bf(a3);
    *(ushort4*)&out[obase + x4] = o;
}

// K1: img f32 -> A bf16
__global__ void hblur_img(const float* __restrict__ in, unsigned short* __restrict__ out,
                          const float* __restrict__ k1g) {
    __shared__ __align__(16) float row[HCOLS + 2 * R + 2];
    const int tid = threadIdx.x;
    const int plane = blockIdx.z, y = blockIdx.y, x0 = blockIdx.x * HCOLS;
    const size_t rb = (size_t)plane * PLANE + (size_t)y * W;
    const float* rin = in + rb;
    {   // interior, vectorized
        int x = x0 + 4 * tid;
        if (x + 3 < W) {
            *(float4*)&row[R + 4 * tid] = *(const float4*)&rin[x];
        } else {
#pragma unroll
            for (int j = 0; j < 4; ++j) row[R + 4 * tid + j] = rin[reflect_idx(x + j, W)];
        }
    }
    if (tid < R) row[tid] = rin[reflect_idx(x0 - R + tid, W)];
    else if (tid < 2 * R) row[HCOLS + R + (tid - R)] = rin[reflect_idx(x0 + HCOLS + (tid - R), W)];
    __syncthreads();
    hconv_store(row, tid, k1g, out, rb, x0);
}

// K3: r bf16 -> mask(0/1) -> hblur -> Bh bf16
__device__ __forceinline__ float maskv(unsigned short u) {
    return (fabsf(bf2f(u)) * 255.f > 10.f) ? 1.f : 0.f;
}
__global__ void hblur_mask(const unsigned short* __restrict__ rbuf,
                           unsigned short* __restrict__ out, const float* __restrict__ k1g) {
    __shared__ __align__(16) float row[HCOLS + 2 * R + 2];
    const int tid = threadIdx.x;
    const int plane = blockIdx.z, y = blockIdx.y, x0 = blockIdx.x * HCOLS;
    const size_t rb = (size_t)plane * PLANE + (size_t)y * W;
    const unsigned short* rin = rbuf + rb;
    {
        int x = x0 + 4 * tid;
        if (x + 3 < W) {
            ushort4 u = *(const ushort4*)&rin[x];
            row[R + 4 * tid + 0] = maskv(u.x);
            row[R + 4 * tid + 1] = maskv(u.y);
            row[R + 4 * tid + 2] = maskv(u.z);
            row[R + 4 * tid + 3] = maskv(u.w);
        } else {
#pragma unroll
            for (int j = 0; j < 4; ++j) row[R + 4 * tid + j] = maskv(rin[reflect_idx(x + j, W)]);
        }
    }
    if (tid < R) row[tid] = maskv(rin[reflect_idx(x0 - R + tid, W)]);
    else if (tid < 2 * R) row[HCOLS + R + (tid - R)] = maskv(rin[reflect_idx(x0 + HCOLS + (tid - R), W)]);
    __syncthreads();
    hconv_store(row, tid, k1g, out, rb, x0);
}

// ---- vertical tile conv: stage SR x CT bf16 in LDS, 9 rows x 4 cols/thread --
__device__ __forceinline__ void vconv_tile(const unsigned short* __restrict__ Ap,
                                           int x0, int y0, const float* __restrict__ k1g,
                                           unsigned short* __restrict__ smem,
                                           float4 acc[9], int tx, int ty) {
    for (int q = threadIdx.x; q < SR * (CT / 4); q += 256) {
        int sr = q >> 5;
        int c4 = (q & 31) * 4;
        int g = reflect_idx(y0 - R + sr, H);
        ushort4 u = *(const ushort4*)(Ap + (size_t)g * W + x0 + c4);
        *(ushort4*)&smem[sr * CT + c4] = u;
    }
    __syncthreads();
#pragma unroll
    for (int j = 0; j < 9; ++j) acc[j] = make_float4(0.f, 0.f, 0.f, 0.f);
    const unsigned short* col = smem + (ty * 9) * CT + tx * 4;
#pragma unroll
    for (int u = 0; u < 59; ++u) {
        ushort4 s = *(const ushort4*)(col + u * CT);
        float4 v = make_float4(bf2f(s.x), bf2f(s.y), bf2f(s.z), bf2f(s.w));
        const int jlo = (u - 50 > 0) ? u - 50 : 0;
        const int jhi = (u < 8) ? u : 8;
#pragma unroll
        for (int j = jlo; j <= jhi; ++j) {
            const float k = k1g[u - j];
            acc[j].x += k * v.x; acc[j].y += k * v.y;
            acc[j].z += k * v.z; acc[j].w += k * v.w;
        }
    }
}

// K2: vblur(A) -> r = img - blur, bf16
__global__ void vblur_r(const unsigned short* __restrict__ A, const float* __restrict__ img,
                        const float* __restrict__ k1g, unsigned short* __restrict__ rbuf) {
    __shared__ unsigned short smem[SR * CT];
    const int plane = blockIdx.z, x0 = blockIdx.x * CT, y0 = blockIdx.y * RT;
    const int tx = threadIdx.x & 31, ty = threadIdx.x >> 5;
    float4 acc[9];
    vconv_tile(A + (size_t)plane * PLANE, x0, y0, k1g, smem, acc, tx, ty);
#pragma unroll
    for (int j = 0; j < 9; ++j) {
        size_t idx = (size_t)plane * PLANE + (size_t)(y0 + ty * 9 + j) * W + x0 + tx * 4;
        float4 iv = *(const float4*)&img[idx];
        ushort4 rr;
        rr.x = f2bf(iv.x - acc[j].x);
        rr.y = f2bf(iv.y - acc[j].y);
        rr.z = f2bf(iv.z - acc[j].z);
        rr.w = f2bf(iv.w - acc[j].w);
        *(ushort4*)&rbuf[idx] = rr;
    }
}

// K4: vblur(Bh) -> soft; out = img + soft * (clip(img+0.5r,0,1)-img)
__global__ void vblur_blend(const unsigned short* __restrict__ Bh, const float* __restrict__ img,
                            const unsigned short* __restrict__ rbuf,
                            const float* __restrict__ k1g, float* __restrict__ out) {
    __shared__ unsigned short smem[SR * CT];
    const int plane = blockIdx.z, x0 = blockIdx.x * CT, y0 = blockIdx.y * RT;
    const int tx = threadIdx.x & 31, ty = threadIdx.x >> 5;
    float4 acc[9];
    vconv_tile(Bh + (size_t)plane * PLANE, x0, y0, k1g, smem, acc, tx, ty);
#pragma unroll
    for (int j = 0; j < 9; ++j) {
        size_t idx = (size_t)plane * PLANE + (size_t)(y0 + ty * 9 + j) * W + x0 + tx * 4;
        float4 iv = *(const float4*)&img[idx];
        ushort4 ru = *(const ushort4*)&rbuf[idx];
        float4 o;
        float dx = fminf(fmaxf(iv.x + 0.5f * bf2f(ru.x), 0.f), 1.f) - iv.x;
        float dy = fminf(fmaxf(iv.y + 0.5f * bf2f(ru.y), 0.f), 1.f) - iv.y;
        float dz = fminf(fmaxf(iv.z + 0.5f * bf2f(ru.z), 0.f), 1.f) - iv.z;
        float dw = fminf(fmaxf(iv.w + 0.5f * bf2f(ru.w), 0.f), 1.f) - iv.w;
        o.x = iv.x + acc[j].x * dx;
        o.y = iv.y + acc[j].y * dy;
        o.z = iv.z + acc[j].z * dz;
        o.w = iv.w + acc[j].w * dw;
        *(float4*)&out[idx] = o;
    }
}

extern "C" void kernel_launch(void* const* d_in, const int* in_sizes, int n_in,
                              void* d_out, int out_size, void* d_ws, size_t ws_size,
                              hipStream_t stream) {
    const float* img = (const float*)d_in[0];
    const float* k2d = (const float*)d_in[1];
    float* out = (float*)d_out;

    unsigned short* AB = (unsigned short*)d_ws;          // A, later Bh
    unsigned short* rbuf = AB + TOT;                     // residual bf16
    float* k1 = (float*)(rbuf + TOT);

    dim3 gridH((W + HCOLS - 1) / HCOLS, H, NP);  // (2, 1080, 6)
    dim3 gridV(W / CT, H / RT, NP);              // (15, 15, 6)

    hipLaunchKernelGGL(compute_k1, dim3(1), dim3(64), 0, stream, k2d, k1);
    hipLaunchKernelGGL(hblur_img, gridH, dim3(256), 0, stream, img, AB, k1);
    hipLaunchKernelGGL(vblur_r, gridV, dim3(256), 0, stream, AB, img, k1, rbuf);
    hipLaunchKernelGGL(hblur_mask, gridH, dim3(256), 0, stream, rbuf, AB, k1);
    hipLaunchKernelGGL(vblur_blend, gridV, dim3(256), 0, stream, AB, img, rbuf, k1, out);
}

// Round 5
// 367.430 us; speedup vs baseline: 1.1166x; 1.1166x over previous
//
#include <hip/hip_runtime.h>

// USMSharp R5: separable Gaussian, bf16 intermediates, all kernels barrier-free.
// K1 hblur8(img f32)->A bf16 ; K2 vblur(A) -> r=img-blur bf16
// K3 hblur8(mask(|r|*255>10))->Bh bf16 (aliases A) ; K4 vblur(Bh)+blend->out.
// vblur: register rolling, (32,8) blocks, XCD-swizzled y-strips for L2 halo reuse.

#define W 1920
#define H 1080
#define NP 6
#define PLANE (H * W)
#define TOT (NP * PLANE)
#define R 25
#define KS 51
#define TV 9                     // rows per thread in vblur
#define NXT 15                   // x tiles of 128 cols
#define NYT 15                   // y tiles of 72 rows
#define WU_TOTAL (NXT * NYT * NP)        // 1350
#define WU_PER_XCD ((WU_TOTAL + 7) / 8)  // 169
#define HPR 240                  // hblur threads per row (8 cols each)

__device__ __forceinline__ int reflect_idx(int i, int n) {
    if (i < 0) i = -i;
    if (i >= n) i = 2 * n - 2 - i;
    return i;
}
__device__ __forceinline__ float bf2f(unsigned short u) {
    return __uint_as_float(((unsigned int)u) << 16);
}
__device__ __forceinline__ unsigned short f2bf(float f) {  // RNE
    unsigned int x = __float_as_uint(f);
    return (unsigned short)((x + 0x7FFFu + ((x >> 16) & 1u)) >> 16);
}
__device__ __forceinline__ float maskv(unsigned short u) {
    return (fabsf(bf2f(u)) * 255.f > 10.f) ? 1.f : 0.f;
}

__global__ void compute_k1(const float* __restrict__ k2d, float* __restrict__ k1) {
    int t = threadIdx.x;
    if (t < KS) {
        float s = 0.f;
        for (int j = 0; j < KS; ++j) s += k2d[t * KS + j];
        k1[t] = s;
    }
}

// ---- horizontal blur: 8 outputs/thread, registers only, no LDS/barrier -----
template <typename T, bool MASK>
__global__ void hblur8(const T* __restrict__ in, unsigned short* __restrict__ out,
                       const float* __restrict__ k1g) {
    const int t = blockIdx.x * 256 + threadIdx.x;
    const int row = t / HPR;                 // 0 .. H*NP-1 (planes contiguous)
    const int c0 = (t - row * HPR) * 8;
    const T* rin = in + (size_t)row * W;
    float f[64];
    if (c0 >= 28 && c0 <= W - 36) {
#pragma unroll
        for (int i = 0; i < 16; ++i) {
            if constexpr (MASK) {
                ushort4 u = *(const ushort4*)&rin[c0 - 28 + 4 * i];
                f[4 * i + 0] = maskv(u.x); f[4 * i + 1] = maskv(u.y);
                f[4 * i + 2] = maskv(u.z); f[4 * i + 3] = maskv(u.w);
            } else {
                float4 v = *(const float4*)&rin[c0 - 28 + 4 * i];
                f[4 * i + 0] = v.x; f[4 * i + 1] = v.y;
                f[4 * i + 2] = v.z; f[4 * i + 3] = v.w;
            }
        }
    } else {
#pragma unroll
        for (int i = 0; i < 64; ++i) {
            int xi = reflect_idx(c0 - 28 + i, W);
            if constexpr (MASK) f[i] = maskv(rin[xi]);
            else f[i] = (float)rin[xi];
        }
    }
    float acc[8];
#pragma unroll
    for (int o = 0; o < 8; ++o) acc[o] = 0.f;
#pragma unroll
    for (int k = 0; k < KS; ++k) {
        const float kk = k1g[k];
#pragma unroll
        for (int o = 0; o < 8; ++o) acc[o] += kk * f[o + 3 + k];
    }
    size_t ob = (size_t)row * W + c0;
    ushort4 o0, o1;
    o0.x = f2bf(acc[0]); o0.y = f2bf(acc[1]); o0.z = f2bf(acc[2]); o0.w = f2bf(acc[3]);
    o1.x = f2bf(acc[4]); o1.y = f2bf(acc[5]); o1.z = f2bf(acc[6]); o1.w = f2bf(acc[7]);
    *(ushort4*)&out[ob] = o0;
    *(ushort4*)&out[ob + 4] = o1;
}

// ---- vertical conv: register rolling, 9 rows x 4 cols per thread -----------
__device__ __forceinline__ bool decode_wu(int lin, int& p, int& yt, int& xt) {
    int c = lin & 7, j = lin >> 3;
    int wu = c * WU_PER_XCD + j;   // XCD c gets a y-contiguous strip of work
    if (wu >= WU_TOTAL) return false;
    p = wu / (NXT * NYT);
    int rem = wu - p * (NXT * NYT);
    yt = rem / NXT;
    xt = rem - yt * NXT;
    return true;
}

__device__ __forceinline__ void vconv9(const unsigned short* __restrict__ Ap, int x4, int y0,
                                       const float* __restrict__ k1g, float4 acc[TV]) {
#pragma unroll
    for (int j = 0; j < TV; ++j) acc[j] = make_float4(0.f, 0.f, 0.f, 0.f);
    if (y0 >= R && y0 + TV - 1 + R < H) {
        const unsigned short* p = Ap + (size_t)(y0 - R) * W + x4;
#pragma unroll
        for (int u = 0; u < TV + 2 * R; ++u) {   // 59 rows
            ushort4 s = *(const ushort4*)p;
            p += W;
            float4 v = make_float4(bf2f(s.x), bf2f(s.y), bf2f(s.z), bf2f(s.w));
            const int jlo = (u - 2 * R > 0) ? u - 2 * R : 0;
            const int jhi = (u < TV - 1) ? u : TV - 1;
#pragma unroll
            for (int j = jlo; j <= jhi; ++j) {
                const float k = k1g[u - j];
                acc[j].x += k * v.x; acc[j].y += k * v.y;
                acc[j].z += k * v.z; acc[j].w += k * v.w;
            }
        }
    } else {
#pragma unroll
        for (int u = 0; u < TV + 2 * R; ++u) {
            int yy = reflect_idx(y0 - R + u, H);
            ushort4 s = *(const ushort4*)(Ap + (size_t)yy * W + x4);
            float4 v = make_float4(bf2f(s.x), bf2f(s.y), bf2f(s.z), bf2f(s.w));
            const int jlo = (u - 2 * R > 0) ? u - 2 * R : 0;
            const int jhi = (u < TV - 1) ? u : TV - 1;
#pragma unroll
            for (int j = jlo; j <= jhi; ++j) {
                const float k = k1g[u - j];
                acc[j].x += k * v.x; acc[j].y += k * v.y;
                acc[j].z += k * v.z; acc[j].w += k * v.w;
            }
        }
    }
}

// K2: vblur(A) -> r = img - blur (bf16)
__global__ void vblur_r(const unsigned short* __restrict__ A, const float* __restrict__ img,
                        const float* __restrict__ k1g, unsigned short* __restrict__ rbuf) {
    int p, yt, xt;
    if (!decode_wu(blockIdx.x, p, yt, xt)) return;
    const int tx = threadIdx.x & 31, ty = threadIdx.x >> 5;
    const int x4 = xt * 128 + tx * 4;
    const int y0 = yt * 72 + ty * TV;
    float4 acc[TV];
    vconv9(A + (size_t)p * PLANE, x4, y0, k1g, acc);
#pragma unroll
    for (int j = 0; j < TV; ++j) {
        size_t idx = (size_t)p * PLANE + (size_t)(y0 + j) * W + x4;
        float4 iv = *(const float4*)&img[idx];
        ushort4 rr;
        rr.x = f2bf(iv.x - acc[j].x);
        rr.y = f2bf(iv.y - acc[j].y);
        rr.z = f2bf(iv.z - acc[j].z);
        rr.w = f2bf(iv.w - acc[j].w);
        *(ushort4*)&rbuf[idx] = rr;
    }
}

// K4: vblur(Bh) -> soft; out = img + soft * (clip(img+0.5r,0,1)-img)
__global__ void vblur_blend(const unsigned short* __restrict__ Bh, const float* __restrict__ img,
                            const unsigned short* __restrict__ rbuf,
                            const float* __restrict__ k1g, float* __restrict__ out) {
    int p, yt, xt;
    if (!decode_wu(blockIdx.x, p, yt, xt)) return;
    const int tx = threadIdx.x & 31, ty = threadIdx.x >> 5;
    const int x4 = xt * 128 + tx * 4;
    const int y0 = yt * 72 + ty * TV;
    float4 acc[TV];
    vconv9(Bh + (size_t)p * PLANE, x4, y0, k1g, acc);
#pragma unroll
    for (int j = 0; j < TV; ++j) {
        size_t idx = (size_t)p * PLANE + (size_t)(y0 + j) * W + x4;
        float4 iv = *(const float4*)&img[idx];
        ushort4 ru = *(const ushort4*)&rbuf[idx];
        float dx = fminf(fmaxf(iv.x + 0.5f * bf2f(ru.x), 0.f), 1.f) - iv.x;
        float dy = fminf(fmaxf(iv.y + 0.5f * bf2f(ru.y), 0.f), 1.f) - iv.y;
        float dz = fminf(fmaxf(iv.z + 0.5f * bf2f(ru.z), 0.f), 1.f) - iv.z;
        float dw = fminf(fmaxf(iv.w + 0.5f * bf2f(ru.w), 0.f), 1.f) - iv.w;
        float4 o;
        o.x = iv.x + acc[j].x * dx;
        o.y = iv.y + acc[j].y * dy;
        o.z = iv.z + acc[j].z * dz;
        o.w = iv.w + acc[j].w * dw;
        *(float4*)&out[idx] = o;
    }
}

extern "C" void kernel_launch(void* const* d_in, const int* in_sizes, int n_in,
                              void* d_out, int out_size, void* d_ws, size_t ws_size,
                              hipStream_t stream) {
    const float* img = (const float*)d_in[0];
    const float* k2d = (const float*)d_in[1];
    float* out = (float*)d_out;

    unsigned short* AB = (unsigned short*)d_ws;  // A, later Bh
    unsigned short* rbuf = AB + TOT;             // residual bf16
    float* k1 = (float*)(rbuf + TOT);

    const int gridHB = (H * NP * HPR) / 256;       // 6075 exact
    const int gridVB = 8 * WU_PER_XCD;             // 1352 (2 idle)

    hipLaunchKernelGGL(compute_k1, dim3(1), dim3(64), 0, stream, k2d, k1);
    hipLaunchKernelGGL((hblur8<float, false>), dim3(gridHB), dim3(256), 0, stream, img, AB, k1);
    hipLaunchKernelGGL(vblur_r, dim3(gridVB), dim3(256), 0, stream, AB, img, k1, rbuf);
    hipLaunchKernelGGL((hblur8<unsigned short, true>), dim3(gridHB), dim3(256), 0, stream, rbuf, AB, k1);
    hipLaunchKernelGGL(vblur_blend, dim3(gridVB), dim3(256), 0, stream, AB, img, rbuf, k1, out);
}

// Round 6
// 230.436 us; speedup vs baseline: 1.7803x; 1.5945x over previous
//
#include <hip/hip_runtime.h>

// USMSharp R6: separable Gaussian, bf16 intermediates, all kernels barrier-free.
// K1 hblur16(img f32)->A bf16 ; K2 vblur(A) -> r=img-blur bf16
// K3 hblur16(mask(|r|*255>10))->Bh bf16 (aliases A) ; K4 vblur(Bh)+blend->out.
// hblur: STREAMING 16-outputs/thread, aligned loads, interior/boundary split grid.
// vblur: register rolling, (32,8) blocks, XCD-swizzled y-strips (unchanged from R5).

#define W 1920
#define H 1080
#define NP 6
#define PLANE (H * W)
#define TOT (NP * PLANE)
#define R 25
#define KS 51
#define TV 9
#define NXT 15
#define NYT 15
#define WU_TOTAL (NXT * NYT * NP)
#define WU_PER_XCD ((WU_TOTAL + 7) / 8)
#define NROWS (H * NP)               // 6480
#define NI (NROWS * 116)             // interior threads (chunks 2..117)
#define NBI ((NI + 255) / 256)       // 2937
#define NB (NROWS * 4)               // boundary threads (chunks 0,1,118,119)
#define NBB ((NB + 255) / 256)       // 102

__device__ __forceinline__ int reflect_idx(int i, int n) {
    if (i < 0) i = -i;
    if (i >= n) i = 2 * n - 2 - i;
    return i;
}
__device__ __forceinline__ float bf2f(unsigned short u) {
    return __uint_as_float(((unsigned int)u) << 16);
}
__device__ __forceinline__ unsigned short f2bf(float f) {  // RNE
    unsigned int x = __float_as_uint(f);
    return (unsigned short)((x + 0x7FFFu + ((x >> 16) & 1u)) >> 16);
}
__device__ __forceinline__ float maskf(float f) {
    return (fabsf(f) * 255.f > 10.f) ? 1.f : 0.f;
}

__global__ void compute_k1(const float* __restrict__ k2d, float* __restrict__ k1) {
    int t = threadIdx.x;
    if (t < KS) {
        float s = 0.f;
        for (int j = 0; j < KS; ++j) s += k2d[t * KS + j];
        k1[t] = s;
    }
}

// acc[o] = sum_k k1[k] * w[o+k+7], window w[i] = x[c0-32+i], i in [0,80)
// element p contributes to acc[o], o in [max(0,p-57), min(15,p-7)]
#define CONTRIB(P, VV)                                                   \
    {                                                                    \
        const int _p = (P);                                              \
        if (_p >= 7 && _p <= 72) {                                       \
            const int _olo = (_p - 57 > 0) ? _p - 57 : 0;                \
            const int _ohi = (_p - 7 < 15) ? _p - 7 : 15;                \
            _Pragma("unroll") for (int o = _olo; o <= _ohi; ++o)         \
                acc[o] += k1g[_p - 7 - o] * (VV);                        \
        }                                                                \
    }

template <bool MASK>
__global__ void hblur16(const void* __restrict__ inv, unsigned short* __restrict__ out,
                        const float* __restrict__ k1g) {
    const int b = blockIdx.x;
    float acc[16];
#pragma unroll
    for (int o = 0; o < 16; ++o) acc[o] = 0.f;
    int row, c0;
    if (b < NBI) {  // ---- interior: chunks 2..117, aligned vector loads ----
        const int t = b * 256 + threadIdx.x;
        if (t >= NI) return;
        row = t / 116;
        c0 = (2 + (t - row * 116)) * 16;
        if constexpr (!MASK) {
            const float* rin = (const float*)inv + (size_t)row * W;
#pragma unroll
            for (int i = 0; i < 20; ++i) {
                float4 v = *(const float4*)(rin + c0 - 32 + 4 * i);
                CONTRIB(4 * i + 0, v.x);
                CONTRIB(4 * i + 1, v.y);
                CONTRIB(4 * i + 2, v.z);
                CONTRIB(4 * i + 3, v.w);
            }
        } else {
            const unsigned short* rin = (const unsigned short*)inv + (size_t)row * W;
#pragma unroll
            for (int i = 0; i < 10; ++i) {
                uint4 u = *(const uint4*)(rin + c0 - 32 + 8 * i);
#pragma unroll
                for (int h = 0; h < 4; ++h) {
                    const unsigned int c = (h == 0) ? u.x : (h == 1) ? u.y : (h == 2) ? u.z : u.w;
                    const float flo = __uint_as_float(c << 16);
                    const float fhi = __uint_as_float(c & 0xffff0000u);
                    CONTRIB(8 * i + 2 * h + 0, maskf(flo));
                    CONTRIB(8 * i + 2 * h + 1, maskf(fhi));
                }
            }
        }
    } else {  // ---- boundary: chunks 0,1,118,119, scalar reflect loads ----
        const int t = (b - NBI) * 256 + threadIdx.x;
        if (t >= NB) return;
        row = t >> 2;
        const int q = t & 3;
        c0 = ((q < 2) ? q : q + 116) * 16;
        if constexpr (!MASK) {
            const float* rin = (const float*)inv + (size_t)row * W;
#pragma unroll
            for (int i = 7; i <= 72; ++i) {
                float vv = rin[reflect_idx(c0 - 32 + i, W)];
                CONTRIB(i, vv);
            }
        } else {
            const unsigned short* rin = (const unsigned short*)inv + (size_t)row * W;
#pragma unroll
            for (int i = 7; i <= 72; ++i) {
                float vv = maskf(bf2f(rin[reflect_idx(c0 - 32 + i, W)]));
                CONTRIB(i, vv);
            }
        }
    }
    // pack 16 bf16 -> 2 x 16B stores
    uint4 o0, o1;
    o0.x = (unsigned int)f2bf(acc[0]) | ((unsigned int)f2bf(acc[1]) << 16);
    o0.y = (unsigned int)f2bf(acc[2]) | ((unsigned int)f2bf(acc[3]) << 16);
    o0.z = (unsigned int)f2bf(acc[4]) | ((unsigned int)f2bf(acc[5]) << 16);
    o0.w = (unsigned int)f2bf(acc[6]) | ((unsigned int)f2bf(acc[7]) << 16);
    o1.x = (unsigned int)f2bf(acc[8]) | ((unsigned int)f2bf(acc[9]) << 16);
    o1.y = (unsigned int)f2bf(acc[10]) | ((unsigned int)f2bf(acc[11]) << 16);
    o1.z = (unsigned int)f2bf(acc[12]) | ((unsigned int)f2bf(acc[13]) << 16);
    o1.w = (unsigned int)f2bf(acc[14]) | ((unsigned int)f2bf(acc[15]) << 16);
    unsigned short* op = out + (size_t)row * W + c0;
    *(uint4*)op = o0;
    *(uint4*)(op + 8) = o1;
}

// ---- vertical conv: register rolling, 9 rows x 4 cols per thread (R5) ------
__device__ __forceinline__ bool decode_wu(int lin, int& p, int& yt, int& xt) {
    int c = lin & 7, j = lin >> 3;
    int wu = c * WU_PER_XCD + j;
    if (wu >= WU_TOTAL) return false;
    p = wu / (NXT * NYT);
    int rem = wu - p * (NXT * NYT);
    yt = rem / NXT;
    xt = rem - yt * NXT;
    return true;
}

__device__ __forceinline__ void vconv9(const unsigned short* __restrict__ Ap, int x4, int y0,
                                       const float* __restrict__ k1g, float4 acc[TV]) {
#pragma unroll
    for (int j = 0; j < TV; ++j) acc[j] = make_float4(0.f, 0.f, 0.f, 0.f);
    if (y0 >= R && y0 + TV - 1 + R < H) {
        const unsigned short* p = Ap + (size_t)(y0 - R) * W + x4;
#pragma unroll
        for (int u = 0; u < TV + 2 * R; ++u) {
            ushort4 s = *(const ushort4*)p;
            p += W;
            float4 v = make_float4(bf2f(s.x), bf2f(s.y), bf2f(s.z), bf2f(s.w));
            const int jlo = (u - 2 * R > 0) ? u - 2 * R : 0;
            const int jhi = (u < TV - 1) ? u : TV - 1;
#pragma unroll
            for (int j = jlo; j <= jhi; ++j) {
                const float k = k1g[u - j];
                acc[j].x += k * v.x; acc[j].y += k * v.y;
                acc[j].z += k * v.z; acc[j].w += k * v.w;
            }
        }
    } else {
#pragma unroll
        for (int u = 0; u < TV + 2 * R; ++u) {
            int yy = reflect_idx(y0 - R + u, H);
            ushort4 s = *(const ushort4*)(Ap + (size_t)yy * W + x4);
            float4 v = make_float4(bf2f(s.x), bf2f(s.y), bf2f(s.z), bf2f(s.w));
            const int jlo = (u - 2 * R > 0) ? u - 2 * R : 0;
            const int jhi = (u < TV - 1) ? u : TV - 1;
#pragma unroll
            for (int j = jlo; j <= jhi; ++j) {
                const float k = k1g[u - j];
                acc[j].x += k * v.x; acc[j].y += k * v.y;
                acc[j].z += k * v.z; acc[j].w += k * v.w;
            }
        }
    }
}

__global__ void vblur_r(const unsigned short* __restrict__ A, const float* __restrict__ img,
                        const float* __restrict__ k1g, unsigned short* __restrict__ rbuf) {
    int p, yt, xt;
    if (!decode_wu(blockIdx.x, p, yt, xt)) return;
    const int tx = threadIdx.x & 31, ty = threadIdx.x >> 5;
    const int x4 = xt * 128 + tx * 4;
    const int y0 = yt * 72 + ty * TV;
    float4 acc[TV];
    vconv9(A + (size_t)p * PLANE, x4, y0, k1g, acc);
#pragma unroll
    for (int j = 0; j < TV; ++j) {
        size_t idx = (size_t)p * PLANE + (size_t)(y0 + j) * W + x4;
        float4 iv = *(const float4*)&img[idx];
        ushort4 rr;
        rr.x = f2bf(iv.x - acc[j].x);
        rr.y = f2bf(iv.y - acc[j].y);
        rr.z = f2bf(iv.z - acc[j].z);
        rr.w = f2bf(iv.w - acc[j].w);
        *(ushort4*)&rbuf[idx] = rr;
    }
}

__global__ void vblur_blend(const unsigned short* __restrict__ Bh, const float* __restrict__ img,
                            const unsigned short* __restrict__ rbuf,
                            const float* __restrict__ k1g, float* __restrict__ out) {
    int p, yt, xt;
    if (!decode_wu(blockIdx.x, p, yt, xt)) return;
    const int tx = threadIdx.x & 31, ty = threadIdx.x >> 5;
    const int x4 = xt * 128 + tx * 4;
    const int y0 = yt * 72 + ty * TV;
    float4 acc[TV];
    vconv9(Bh + (size_t)p * PLANE, x4, y0, k1g, acc);
#pragma unroll
    for (int j = 0; j < TV; ++j) {
        size_t idx = (size_t)p * PLANE + (size_t)(y0 + j) * W + x4;
        float4 iv = *(const float4*)&img[idx];
        ushort4 ru = *(const ushort4*)&rbuf[idx];
        float dx = fminf(fmaxf(iv.x + 0.5f * bf2f(ru.x), 0.f), 1.f) - iv.x;
        float dy = fminf(fmaxf(iv.y + 0.5f * bf2f(ru.y), 0.f), 1.f) - iv.y;
        float dz = fminf(fmaxf(iv.z + 0.5f * bf2f(ru.z), 0.f), 1.f) - iv.z;
        float dw = fminf(fmaxf(iv.w + 0.5f * bf2f(ru.w), 0.f), 1.f) - iv.w;
        float4 o;
        o.x = iv.x + acc[j].x * dx;
        o.y = iv.y + acc[j].y * dy;
        o.z = iv.z + acc[j].z * dz;
        o.w = iv.w + acc[j].w * dw;
        *(float4*)&out[idx] = o;
    }
}

extern "C" void kernel_launch(void* const* d_in, const int* in_sizes, int n_in,
                              void* d_out, int out_size, void* d_ws, size_t ws_size,
                              hipStream_t stream) {
    const float* img = (const float*)d_in[0];
    const float* k2d = (const float*)d_in[1];
    float* out = (float*)d_out;

    unsigned short* AB = (unsigned short*)d_ws;  // A, later Bh
    unsigned short* rbuf = AB + TOT;             // residual bf16
    float* k1 = (float*)(rbuf + TOT);

    const int gridHB = NBI + NBB;        // 3039
    const int gridVB = 8 * WU_PER_XCD;   // 1352

    hipLaunchKernelGGL(compute_k1, dim3(1), dim3(64), 0, stream, k2d, k1);
    hipLaunchKernelGGL((hblur16<false>), dim3(gridHB), dim3(256), 0, stream, (const void*)img, AB, k1);
    hipLaunchKernelGGL(vblur_r, dim3(gridVB), dim3(256), 0, stream, AB, img, k1, rbuf);
    hipLaunchKernelGGL((hblur16<true>), dim3(gridHB), dim3(256), 0, stream, (const void*)rbuf, AB, k1);
    hipLaunchKernelGGL(vblur_blend, dim3(gridVB), dim3(256), 0, stream, AB, img, rbuf, k1, out);
}